// Round 5
// baseline (1050.092 us; speedup 1.0000x reference)
//
#include <hip/hip_runtime.h>
#include <math.h>

#define TSTEPS 12
#define BATCH  2048
#define IMG    512
#define HIDN   1024
#define NCLASS 51
#define SCALE_X 1.7320508075688772f      // sqrt(1 + 2*e^0) = sqrt(3)

typedef __attribute__((ext_vector_type(8)))  _Float16 f16x8;
typedef __attribute__((ext_vector_type(2)))  _Float16 f16x2;
typedef __attribute__((ext_vector_type(16))) float    f32x16;

__device__ __forceinline__ float sigf(float x) {
    return 1.f / (1.f + __expf(-x));
}

// s_waitcnt imm: vmcnt low bits [3:0], hi bits [15:14]; lgkmcnt=15 (no wait),
// expcnt=7 (no wait). Supports n up to 63.
#define VMCNT_IMM(n) (0x0F70 | ((n) & 15) | (((n) >> 4) << 14))

// ===========================================================================
// Fragment-ordered layout: matrix [R x K] fp16 stored as 1KB chunks over
// (rt=row/32, kt=k/16); chunk idx = rt*(K/16)+kt; lane l owns halfs
// [l*8,l*8+8) = (row = rt*32+(l&31), k = kt*16+(l>>5)*8+j). Matches the
// v_mfma_f32_32x32x16_f16 A/B fragment.
// ===========================================================================

// ---------------------------------------------------------------------------
// Fused fp16 MFMA GEMM + SRU recurrence. 32x32x16 MFMA.
//
// R14 = R13's intended schedule, with the register hazard fixed:
//  * B is held in FOUR half-banks (bW,bX,bY,bZ), rotated with period 2 via a
//    2x-unrolled step loop so every bank index is compile-time static
//    (runtime-indexed ext_vector arrays would spill to scratch).  Step v
//    consumes {W,X} -- both loaded during step v-1 (full-step lead) -- and
//    loads {Y,Z} = B(v+1); odd steps swap roles.  R13's bug was loading
//    B(v+1) into the SAME named bank the current step's MFMAs still read.
//  * Issue order per step: loadB(H0) -> sched_barrier -> stageA(v+2) ->
//    MFMA(H0) -> barrier -> loadB(H1) -> MFMA(H1).  In-order vmcnt: forcing
//    the H0 bank never transitively forces a pending A-stage (H0-load is
//    older than stage(v+1)); forcing the H1 bank forces stage(v+1) with a
//    full-step lead (covers HBM latency).
//  * Manual top-of-step wait vm(6+4TJ): at v=0 it forces stage(0) exactly
//    (newer = stage(1)[6]+W[2TJ]+X[2TJ]); in steady state it is a no-stall
//    belt (outstanding = H0[2TJ]+stage(v+1)[6]+H1[2TJ] = 6+4TJ), and
//    stage(v) is already forced transitively by step v-1's H1 data-dep wait.
//  * Two barriers per step (uniform control flow) + s_setprio(1) around each
//    MFMA cluster (T5 on a phase-split structure).
// Requires K % 128 == 0 (NV even; 512, 1024 here).
// ---------------------------------------------------------------------------
template<int TJ, int NCOMP>
__global__ __launch_bounds__(256, 2)
void gemm_sru(const _Float16* __restrict__ A, const _Float16* __restrict__ Bt,
              const _Float16* __restrict__ resid,
              const float* __restrict__ vc, const float* __restrict__ bias,
              _Float16* __restrict__ hout, float* __restrict__ hbar, int K,
              int pcshift) {
    constexpr int BN    = 64 * TJ;
    constexpr int NCH   = BN / NCOMP;
    constexpr int ATILE = 192 * 64;            // halfs per A buffer (24 KB)
    constexpr int EPAD  = BN + 8;
    constexpr int EPI   = 96 * EPAD;
    constexpr int HREG  = 96 * NCH;
    constexpr int KTH   = NCH / 16;
    constexpr int PAIRS = NCH / 2;
    constexpr int STG   = 3 * ATILE;           // 3-buffer ring (72 KB)
    constexpr int TOT   = STG > (EPI + HREG) ? STG : (EPI + HREG);
    __shared__ __align__(16) _Float16 smem[TOT];

    const int tid  = threadIdx.x;
    const int lane = tid & 63;
    const int w    = tid >> 6;

    // ---- XCD swizzle: columns ≡ xk (mod 8) stay on one XCD (W-stationary) --
    const int nbx = gridDim.x;
    const int b   = blockIdx.y * nbx + blockIdx.x;
    const int pc1 = (nbx >> 3) - 1;
    const int xk  = b & 7, s = b >> 3;
    const int bx  = xk + ((s & pc1) << 3);
    const int by  = s >> pcshift;

    const int bm  = by * 192;
    const int KT  = K >> 4;

    // ---- A staging: each wave stages 6 of the 24 chunk-loads per 64-k step -
    const int rt0 = bm >> 5;
    auto stageA = [&](int buf, int k0) {
        const int kt0 = k0 >> 4;
        #pragma unroll
        for (int i = 0; i < 6; ++i) {
            const int L = w * 6 + i, rc = L >> 2, kk = L & 3;
            const _Float16* g = A + ((size_t)(rt0 + rc) * KT + kt0 + kk) * 512 + (lane << 3);
            __builtin_amdgcn_global_load_lds(
                (const __attribute__((address_space(1))) unsigned int*)g,
                (__attribute__((address_space(3))) unsigned int*)(smem + buf * ATILE + L * 512),
                16, 0, 0);
        }
    };

    const int wy32 = (w >> 1) * 3;             // wave row-chunk origin
    const int wx32 = (w & 1) * TJ;             // wave col-chunk origin
    const int l5   = lane >> 5;
    const int m32  = lane & 31;

    // B fragment base: chunk (bx*(BN/32) + wx32 + j, kt)
    const _Float16* bglob = Bt + (size_t)(bx * (BN >> 5) + wx32) * KT * 512 + (lane << 3);

    // Four half-banks, statically indexed (period-2 rotation via unroll-2).
    f16x8 bW[2][TJ], bX[2][TJ], bY[2][TJ], bZ[2][TJ];

#define LOADB(DST, k0v)                                                        \
    do {                                                                       \
        const int kt0_ = (k0v) >> 4;                                           \
        _Pragma("unroll")                                                      \
        for (int ks = 0; ks < 2; ++ks)                                         \
            _Pragma("unroll")                                                  \
            for (int j = 0; j < TJ; ++j)                                       \
                DST[ks][j] = *(const f16x8*)&bglob[((size_t)j * KT + kt0_ + ks) * 512]; \
    } while (0)

#define MFMA_HALF(BANK, KSB)                                                   \
    do {                                                                       \
        _Pragma("unroll")                                                      \
        for (int ks = 0; ks < 2; ++ks) {                                       \
            f16x8 a_[3];                                                       \
            _Pragma("unroll")                                                  \
            for (int i = 0; i < 3; ++i)                                        \
                a_[i] = *(const f16x8*)&la[((wy32 + i) * 4 + (KSB) + ks) * 512 + (lane << 3)]; \
            _Pragma("unroll")                                                  \
            for (int i = 0; i < 3; ++i)                                        \
                _Pragma("unroll")                                              \
                for (int j = 0; j < TJ; ++j)                                   \
                    acc[i][j] = __builtin_amdgcn_mfma_f32_32x32x16_f16(        \
                        a_[i], BANK[ks][j], acc[i][j], 0, 0, 0);               \
        }                                                                      \
    } while (0)

#define KSTEP(vv, CONS0, CONS1, FILL0, FILL1)                                  \
    do {                                                                       \
        __builtin_amdgcn_s_waitcnt(VMCNT_IMM(6 + 4 * TJ));                     \
        __builtin_amdgcn_s_barrier();                                          \
        const _Float16* la = smem + rb * ATILE;                                \
        if ((vv) + 1 < NV) LOADB(FILL0, ((vv) + 1) << 6);                      \
        __builtin_amdgcn_sched_barrier(0);                                     \
        if ((vv) + 2 < NV) stageA(sb, ((vv) + 2) << 6);                        \
        __builtin_amdgcn_s_setprio(1);                                         \
        MFMA_HALF(CONS0, 0);                                                   \
        __builtin_amdgcn_s_setprio(0);                                         \
        __builtin_amdgcn_s_barrier();                                          \
        if ((vv) + 1 < NV) LOADB(FILL1, (((vv) + 1) << 6) + 32);               \
        __builtin_amdgcn_s_setprio(1);                                         \
        MFMA_HALF(CONS1, 2);                                                   \
        __builtin_amdgcn_s_setprio(0);                                         \
        rb = (rb == 2) ? 0 : rb + 1;                                           \
        sb = (sb == 2) ? 0 : sb + 1;                                           \
    } while (0)

    f32x16 acc[3][TJ];
    #pragma unroll
    for (int i = 0; i < 3; ++i)
        #pragma unroll
        for (int j = 0; j < TJ; ++j)
            #pragma unroll
            for (int r = 0; r < 16; ++r) acc[i][j][r] = 0.f;

    const int NV = K >> 6;                     // 64-k steps (8 or 16), even

    // Prologue: stage(0), stage(1), B(0,H0)->W, B(0,H1)->X.
    stageA(0, 0);
    stageA(1, 64);
    LOADB(bW, 0);
    LOADB(bX, 32);

    int rb = 0, sb = 2;                        // read buf (v%3), stage buf ((v+2)%3)
    for (int v = 0; v < NV; v += 2) {
        KSTEP(v,     bW, bX, bY, bZ);          // even: consume W,X; fill Y,Z
        KSTEP(v + 1, bY, bZ, bW, bX);          // odd : consume Y,Z; fill W,X
    }

#undef KSTEP
#undef MFMA_HALF
#undef LOADB

    // ---- epilogue: two passes of 96 rows (8 whole batches each) ------------
    _Float16 (*uld)[EPAD] = (_Float16 (*)[EPAD])smem;
    _Float16* hreg = smem + EPI;
    const int bl   = tid / PAIRS;
    const int pr   = tid % PAIRS;
    const int gcol = bx * NCH + pr * 2;

    #pragma unroll
    for (int pass = 0; pass < 2; ++pass) {
        __syncthreads();
        if ((w >> 1) == pass) {
            #pragma unroll
            for (int i = 0; i < 3; ++i)
                #pragma unroll
                for (int j = 0; j < TJ; ++j)
                    #pragma unroll
                    for (int r = 0; r < 16; ++r) {
                        const int row = i * 32 + (r & 3) + 8 * (r >> 2) + 4 * l5;
                        uld[row][(wx32 + j) * 32 + m32] = (_Float16)acc[i][j][r];
                    }
        }
        __syncthreads();

        if (tid < 8 * PAIRS) {
            const float2 vf  = *(const float2*)&vc[gcol];
            const float2 vr  = *(const float2*)&vc[HIDN + gcol];
            const float2 bfv = *(const float2*)&bias[gcol];
            const float2 brv = *(const float2*)&bias[HIDN + gcol];
            const int ca = (pr * 2) * NCOMP, cb = (pr * 2 + 1) * NCOMP;

            float c0 = 0.f, c1 = 0.f, s0 = 0.f, s1 = 0.f;
            #pragma unroll
            for (int t = 0; t < TSTEPS; ++t) {
                const int row = bl * 12 + t;
                const float u0a = (float)uld[row][ca + 0];
                const float u1a = (float)uld[row][ca + 1];
                const float u2a = (float)uld[row][ca + 2];
                const float u0b = (float)uld[row][cb + 0];
                const float u1b = (float)uld[row][cb + 1];
                const float u2b = (float)uld[row][cb + 2];
                float xta, xtb;
                if (NCOMP == 4) {
                    xta = (float)uld[row][ca + 3];
                    xtb = (float)uld[row][cb + 3];
                } else {
                    const int grow = bm + pass * 96 + row;
                    const size_t gran = ((size_t)(grow >> 5) * KT + (gcol >> 4)) * 512
                                      + (size_t)((grow & 31) + ((gcol >> 3) & 1) * 32) * 8
                                      + (gcol & 7);
                    const f16x2 xv = *(const f16x2*)&resid[gran];
                    xta = (float)xv[0]; xtb = (float)xv[1];
                }

                const float f0 = sigf(u1a + vf.x * c0 + bfv.x);
                c0 = f0 * c0 + (1.f - f0) * u0a;
                const float r0_ = sigf(u2a + vr.x * c0 + brv.x);
                const float th0 = 2.f * sigf(2.f * c0) - 1.f;
                const float hv0 = r0_ * th0 + (1.f - r0_) * xta * SCALE_X;

                const float f1 = sigf(u1b + vf.y * c1 + bfv.y);
                c1 = f1 * c1 + (1.f - f1) * u0b;
                const float r1_ = sigf(u2b + vr.y * c1 + brv.y);
                const float th1 = 2.f * sigf(2.f * c1) - 1.f;
                const float hv1 = r1_ * th1 + (1.f - r1_) * xtb * SCALE_X;

                if (hout) {
                    const int rtl  = row >> 5;
                    const int ktl  = pr >> 3;
                    const int lloc = (row & 31) + ((pr >> 2) & 1) * 32;
                    f16x2 hv = { (_Float16)hv0, (_Float16)hv1 };
                    *(f16x2*)&hreg[(rtl * KTH + ktl) * 512 + lloc * 8 + (pr & 3) * 2] = hv;
                }
                s0 += hv0; s1 += hv1;
            }
            if (hbar) {
                const int gb = bm / 12 + pass * 8 + bl;
                *(float2*)&hbar[(size_t)gb * HIDN + gcol] =
                    make_float2(s0 * (1.f / TSTEPS), s1 * (1.f / TSTEPS));
            }
        }

        if (hout) {
            __syncthreads();
            const int rtg0 = (bm + pass * 96) >> 5;
            for (int g = tid; g < HREG / 8; g += 256) {
                const int c = g >> 6, l = g & 63;
                const f16x8 v = *(const f16x8*)&hreg[c * 512 + l * 8];
                const int rtl = c / KTH, ktl = c % KTH;
                const size_t gc = (size_t)(rtg0 + rtl) * 64 + bx * KTH + ktl;
                *(f16x8*)&hout[gc * 512 + l * 8] = v;
            }
        }
    }
}

// ---------------------------------------------------------------------------
// Weight prep (coalesced, LDS transpose): W (K x N fp32, col n = comp*1024+h)
// -> fragment-ordered fp16 plane, row n' = h*NC + comp.
// ---------------------------------------------------------------------------
template<int NC>
__global__ __launch_bounds__(256)
void wsplit_t(const float* __restrict__ W, _Float16* __restrict__ Wt, int K) {
    __shared__ _Float16 tile[32][132];
    const int N  = NC * 1024;
    const int KT = K >> 4;
    const int rt = blockIdx.x, kc = blockIdx.y;

    const int nl = threadIdx.x & 31;
    const int kl = threadIdx.x >> 5;
    const int np = rt * 32 + nl;
    const int h  = np / NC, comp = np - h * NC;
    const int n  = comp * 1024 + h;
    #pragma unroll
    for (int kk = 0; kk < 16; ++kk) {
        const int k = kc * 128 + kl * 16 + kk;
        tile[nl][kl * 16 + kk] = (_Float16)W[(size_t)k * N + n];
    }
    __syncthreads();

    #pragma unroll
    for (int p = 0; p < 2; ++p) {
        const int slot = p * 256 + threadIdx.x;
        const int ktl  = slot >> 6, l = slot & 63;
        f16x8 v;
        #pragma unroll
        for (int j = 0; j < 8; ++j)
            v[j] = tile[l & 31][ktl * 16 + ((l >> 5) << 3) + j];
        const int kt = kc * 8 + ktl;
        *(f16x8*)&Wt[((size_t)rt * KT + kt) * 512 + l * 8] = v;
    }
}

// ---------------------------------------------------------------------------
// x (rows x 512 fp32 row-major) -> fragment-ordered fp16.
// ---------------------------------------------------------------------------
__global__ __launch_bounds__(256)
void esplit(const float* __restrict__ src, _Float16* __restrict__ dst) {
    __shared__ _Float16 tile[32][132];
    const int rt = blockIdx.x, kc = blockIdx.y;
    const int kli = threadIdx.x & 31;
    const int rl  = threadIdx.x >> 5;
    #pragma unroll
    for (int rr = 0; rr < 4; ++rr) {
        const int row = rl * 4 + rr;
        const float4 v = *(const float4*)&src[(size_t)(rt * 32 + row) * 512 + kc * 128 + kli * 4];
        tile[row][kli * 4 + 0] = (_Float16)v.x;
        tile[row][kli * 4 + 1] = (_Float16)v.y;
        tile[row][kli * 4 + 2] = (_Float16)v.z;
        tile[row][kli * 4 + 3] = (_Float16)v.w;
    }
    __syncthreads();

    #pragma unroll
    for (int p = 0; p < 2; ++p) {
        const int slot = p * 256 + threadIdx.x;
        const int ktl  = slot >> 6, l = slot & 63;
        f16x8 v;
        #pragma unroll
        for (int j = 0; j < 8; ++j)
            v[j] = tile[l & 31][ktl * 16 + ((l >> 5) << 3) + j];
        const int kt = kc * 8 + ktl;
        *(f16x8*)&dst[((size_t)rt * 32 + kt) * 512 + l * 8] = v;
    }
}

// ---------------------------------------------------------------------------
// Final FC on time-averaged h: out[b,c] = hbar[b,:] . fc_w[:,c] + fc_b[c]
// ---------------------------------------------------------------------------
__global__ __launch_bounds__(64)
void final_fc(const float* __restrict__ hbar, const float* __restrict__ fcw,
              const float* __restrict__ fcb, float* __restrict__ out) {
    __shared__ float hrow[HIDN];
    const int b = blockIdx.x;
    for (int i = threadIdx.x; i < HIDN; i += 64)
        hrow[i] = hbar[(size_t)b * HIDN + i];
    __syncthreads();

    const int c = threadIdx.x;
    if (c < NCLASS) {
        float acc = fcb[c];
        #pragma unroll 8
        for (int k = 0; k < HIDN; ++k)
            acc = fmaf(hrow[k], fcw[(size_t)k * NCLASS + c], acc);
        out[(size_t)b * NCLASS + c] = acc;
    }
}

// ---------------------------------------------------------------------------
extern "C" void kernel_launch(void* const* d_in, const int* in_sizes, int n_in,
                              void* d_out, int out_size, void* d_ws, size_t ws_size,
                              hipStream_t stream) {
    const float* x   = (const float*)d_in[0];
    const float* W0  = (const float*)d_in[1];
    const float* W1  = (const float*)d_in[2];
    const float* W2  = (const float*)d_in[3];
    const float* vc0 = (const float*)d_in[4];
    const float* vc1 = (const float*)d_in[5];
    const float* vc2 = (const float*)d_in[6];
    const float* b0  = (const float*)d_in[7];
    const float* b1  = (const float*)d_in[8];
    const float* b2  = (const float*)d_in[9];
    const float* fcw = (const float*)d_in[10];
    const float* fcb = (const float*)d_in[11];
    float* out = (float*)d_out;

    char* ws = (char*)d_ws;
    size_t off = 0;
    auto carve = [&](size_t bytes) { char* p = ws + off; off = (off + bytes + 255) & ~255ull; return p; };

    _Float16* W0t = (_Float16*)carve((size_t)4096 * 512 * 2);
    _Float16* W1t = (_Float16*)carve((size_t)3072 * 1024 * 2);
    _Float16* W2t = (_Float16*)carve((size_t)3072 * 1024 * 2);
    const size_t W_BYTES = off;

    const size_t PER_B = 12ull * 512 * 2 + 2ull * 12 * 1024 * 2 + 1024ull * 4 + 1024;
    int CB = 32;
    if      (W_BYTES + 2048ull * PER_B <= ws_size) CB = 2048;
    else if (W_BYTES + 1024ull * PER_B <= ws_size) CB = 1024;
    else if (W_BYTES +  512ull * PER_B <= ws_size) CB = 512;
    else if (W_BYTES +  256ull * PER_B <= ws_size) CB = 256;
    else if (W_BYTES +  128ull * PER_B <= ws_size) CB = 128;
    else if (W_BYTES +   64ull * PER_B <= ws_size) CB = 64;
    const int MC = CB * TSTEPS;

    _Float16* x16  = (_Float16*)carve((size_t)MC * 512 * 2);
    _Float16* hA16 = (_Float16*)carve((size_t)MC * 1024 * 2);
    _Float16* hB16 = (_Float16*)carve((size_t)MC * 1024 * 2);
    float*    hbar = (float*)carve((size_t)CB * 1024 * 4);

    const dim3 blk256(256);

    wsplit_t<4><<<dim3(4096 / 32, 512 / 128),  blk256, 0, stream>>>(W0, W0t, 512);
    wsplit_t<3><<<dim3(3072 / 32, 1024 / 128), blk256, 0, stream>>>(W1, W1t, 1024);
    wsplit_t<3><<<dim3(3072 / 32, 1024 / 128), blk256, 0, stream>>>(W2, W2t, 1024);

    for (int cb = 0; cb < BATCH / CB; ++cb) {
        const float* xc   = x   + (size_t)cb * CB * TSTEPS * IMG;
        float*       outc = out + (size_t)cb * CB * NCLASS;

        // layer 0: x -> fragment fp16; fused GEMM(K=512, BN=128, NCOMP=4)
        esplit<<<dim3(MC / 32, 4), blk256, 0, stream>>>(xc, x16);
        gemm_sru<2, 4><<<dim3(4096 / 128, MC / 192), blk256, 0, stream>>>(
            x16, W0t, nullptr, vc0, b0, hA16, nullptr, 512, 2);   // pc=4

        // layer 1: fused GEMM(K=1024, BN=192, NCOMP=3)
        gemm_sru<3, 3><<<dim3(3072 / 192, MC / 192), blk256, 0, stream>>>(
            hA16, W1t, hA16, vc1, b1, hB16, nullptr, 1024, 1);    // pc=2

        // layer 2: fused; emit hbar only
        gemm_sru<3, 3><<<dim3(3072 / 192, MC / 192), blk256, 0, stream>>>(
            hB16, W2t, hB16, vc2, b2, nullptr, hbar, 1024, 1);

        final_fc<<<dim3(CB), dim3(64), 0, stream>>>(hbar, fcw, fcb, outc);
    }
}

// Round 6
// 1022.531 us; speedup vs baseline: 1.0270x; 1.0270x over previous
//
#include <hip/hip_runtime.h>
#include <math.h>

#define TSTEPS 12
#define BATCH  2048
#define IMG    512
#define HIDN   1024
#define NCLASS 51
#define SCALE_X 1.7320508075688772f      // sqrt(1 + 2*e^0) = sqrt(3)

typedef __attribute__((ext_vector_type(8)))  _Float16 f16x8;
typedef __attribute__((ext_vector_type(2)))  _Float16 f16x2;
typedef __attribute__((ext_vector_type(16))) float    f32x16;

__device__ __forceinline__ float sigf(float x) {
    return 1.f / (1.f + __expf(-x));
}

// ===========================================================================
// Fragment-ordered layout: matrix [R x K] fp16 stored as 1KB chunks over
// (rt=row/32, kt=k/16); chunk idx = rt*(K/16)+kt; lane l owns halfs
// [l*8,l*8+8) = (row = rt*32+(l&31), k = kt*16+(l>>5)*8+j). Matches the
// v_mfma_f32_32x32x16_f16 A/B fragment.
// ===========================================================================

// ---------------------------------------------------------------------------
// Fused fp16 MFMA GEMM + SRU recurrence. 32x32x16 MFMA.
//
// R15: BARRIER-FREE K-loop. A is fragment-ordered in the workspace (same
// as B), so each wave loads its A fragments DIRECTLY from global -- no LDS
// staging, no s_barrier, no manual vmcnt in the K-loop at all. Waves run
// fully independently; the compiler emits per-use counted vmcnt and hoists
// next-chunk loads only while registers are free (R5's manual 4-bank
// variant spilled: 144 acc + 96 banks > 256-reg budget at 2 blocks/CU).
// Cost: A is fetched by both wave-columns (2x) -- the second read is an
// immediate L2 hit (L2 at 33% util, HBM at 17%: headroom). LDS is used
// only by the SRU epilogue (50688 B -> 2 blocks/CU preserved).
// Rationale: R0-R5 lockstep variants all pin at 30-34% MfmaUtil; the
// barrier-drain structure itself is the bottleneck (m233 signature), so
// this round ablates the structure, not the schedule.
// ---------------------------------------------------------------------------
template<int TJ, int NCOMP>
__global__ __launch_bounds__(256, 2)
void gemm_sru(const _Float16* __restrict__ A, const _Float16* __restrict__ Bt,
              const _Float16* __restrict__ resid,
              const float* __restrict__ vc, const float* __restrict__ bias,
              _Float16* __restrict__ hout, float* __restrict__ hbar, int K,
              int pcshift) {
    constexpr int BN    = 64 * TJ;
    constexpr int NCH   = BN / NCOMP;
    constexpr int EPAD  = BN + 8;
    constexpr int EPI   = 96 * EPAD;
    constexpr int HREG  = 96 * NCH;
    constexpr int KTH   = NCH / 16;
    constexpr int PAIRS = NCH / 2;
    __shared__ __align__(16) _Float16 smem[EPI + HREG];

    const int tid  = threadIdx.x;
    const int lane = tid & 63;
    const int w    = tid >> 6;

    // ---- XCD swizzle: columns ≡ xk (mod 8) stay on one XCD (W-stationary) --
    const int nbx = gridDim.x;
    const int b   = blockIdx.y * nbx + blockIdx.x;
    const int pc1 = (nbx >> 3) - 1;
    const int xk  = b & 7, s = b >> 3;
    const int bx  = xk + ((s & pc1) << 3);
    const int by  = s >> pcshift;

    const int bm  = by * 192;
    const int KT  = K >> 4;
    const int rt0 = bm >> 5;

    const int wy32 = (w >> 1) * 3;             // wave row-chunk origin
    const int wx32 = (w & 1) * TJ;             // wave col-chunk origin
    const int l5   = lane >> 5;
    const int m32  = lane & 31;

    // Per-wave fragment bases (both planes are fragment-ordered).
    const _Float16* aglob = A  + (size_t)(rt0 + wy32) * KT * 512 + (lane << 3);
    const _Float16* bglob = Bt + (size_t)(bx * (BN >> 5) + wx32) * KT * 512 + (lane << 3);

    f32x16 acc[3][TJ];
    #pragma unroll
    for (int i = 0; i < 3; ++i)
        #pragma unroll
        for (int j = 0; j < TJ; ++j)
            #pragma unroll
            for (int r = 0; r < 16; ++r) acc[i][j][r] = 0.f;

    // ---- barrier-free K-loop: 6 coalesced 1KB loads + 9 MFMAs per 16-k ----
    #pragma unroll 4
    for (int kt = 0; kt < KT; ++kt) {
        f16x8 av[3], bv[TJ];
        #pragma unroll
        for (int i = 0; i < 3; ++i)
            av[i] = *(const f16x8*)&aglob[((size_t)i * KT + kt) * 512];
        #pragma unroll
        for (int j = 0; j < TJ; ++j)
            bv[j] = *(const f16x8*)&bglob[((size_t)j * KT + kt) * 512];
        #pragma unroll
        for (int i = 0; i < 3; ++i)
            #pragma unroll
            for (int j = 0; j < TJ; ++j)
                acc[i][j] = __builtin_amdgcn_mfma_f32_32x32x16_f16(
                    av[i], bv[j], acc[i][j], 0, 0, 0);
    }

    // ---- epilogue: two passes of 96 rows (8 whole batches each) ------------
    _Float16 (*uld)[EPAD] = (_Float16 (*)[EPAD])smem;
    _Float16* hreg = smem + EPI;
    const int bl   = tid / PAIRS;
    const int pr   = tid % PAIRS;
    const int gcol = bx * NCH + pr * 2;

    #pragma unroll
    for (int pass = 0; pass < 2; ++pass) {
        __syncthreads();
        if ((w >> 1) == pass) {
            #pragma unroll
            for (int i = 0; i < 3; ++i)
                #pragma unroll
                for (int j = 0; j < TJ; ++j)
                    #pragma unroll
                    for (int r = 0; r < 16; ++r) {
                        const int row = i * 32 + (r & 3) + 8 * (r >> 2) + 4 * l5;
                        uld[row][(wx32 + j) * 32 + m32] = (_Float16)acc[i][j][r];
                    }
        }
        __syncthreads();

        if (tid < 8 * PAIRS) {
            const float2 vf  = *(const float2*)&vc[gcol];
            const float2 vr  = *(const float2*)&vc[HIDN + gcol];
            const float2 bfv = *(const float2*)&bias[gcol];
            const float2 brv = *(const float2*)&bias[HIDN + gcol];
            const int ca = (pr * 2) * NCOMP, cb = (pr * 2 + 1) * NCOMP;

            float c0 = 0.f, c1 = 0.f, s0 = 0.f, s1 = 0.f;
            #pragma unroll
            for (int t = 0; t < TSTEPS; ++t) {
                const int row = bl * 12 + t;
                const float u0a = (float)uld[row][ca + 0];
                const float u1a = (float)uld[row][ca + 1];
                const float u2a = (float)uld[row][ca + 2];
                const float u0b = (float)uld[row][cb + 0];
                const float u1b = (float)uld[row][cb + 1];
                const float u2b = (float)uld[row][cb + 2];
                float xta, xtb;
                if (NCOMP == 4) {
                    xta = (float)uld[row][ca + 3];
                    xtb = (float)uld[row][cb + 3];
                } else {
                    const int grow = bm + pass * 96 + row;
                    const size_t gran = ((size_t)(grow >> 5) * KT + (gcol >> 4)) * 512
                                      + (size_t)((grow & 31) + ((gcol >> 3) & 1) * 32) * 8
                                      + (gcol & 7);
                    const f16x2 xv = *(const f16x2*)&resid[gran];
                    xta = (float)xv[0]; xtb = (float)xv[1];
                }

                const float f0 = sigf(u1a + vf.x * c0 + bfv.x);
                c0 = f0 * c0 + (1.f - f0) * u0a;
                const float r0_ = sigf(u2a + vr.x * c0 + brv.x);
                const float th0 = 2.f * sigf(2.f * c0) - 1.f;
                const float hv0 = r0_ * th0 + (1.f - r0_) * xta * SCALE_X;

                const float f1 = sigf(u1b + vf.y * c1 + bfv.y);
                c1 = f1 * c1 + (1.f - f1) * u0b;
                const float r1_ = sigf(u2b + vr.y * c1 + brv.y);
                const float th1 = 2.f * sigf(2.f * c1) - 1.f;
                const float hv1 = r1_ * th1 + (1.f - r1_) * xtb * SCALE_X;

                if (hout) {
                    const int rtl  = row >> 5;
                    const int ktl  = pr >> 3;
                    const int lloc = (row & 31) + ((pr >> 2) & 1) * 32;
                    f16x2 hv = { (_Float16)hv0, (_Float16)hv1 };
                    *(f16x2*)&hreg[(rtl * KTH + ktl) * 512 + lloc * 8 + (pr & 3) * 2] = hv;
                }
                s0 += hv0; s1 += hv1;
            }
            if (hbar) {
                const int gb = bm / 12 + pass * 8 + bl;
                *(float2*)&hbar[(size_t)gb * HIDN + gcol] =
                    make_float2(s0 * (1.f / TSTEPS), s1 * (1.f / TSTEPS));
            }
        }

        if (hout) {
            __syncthreads();
            const int rtg0 = (bm + pass * 96) >> 5;
            for (int g = tid; g < HREG / 8; g += 256) {
                const int c = g >> 6, l = g & 63;
                const f16x8 v = *(const f16x8*)&hreg[c * 512 + l * 8];
                const int rtl = c / KTH, ktl = c % KTH;
                const size_t gc = (size_t)(rtg0 + rtl) * 64 + bx * KTH + ktl;
                *(f16x8*)&hout[gc * 512 + l * 8] = v;
            }
        }
    }
}

// ---------------------------------------------------------------------------
// Weight prep (coalesced, LDS transpose): W (K x N fp32, col n = comp*1024+h)
// -> fragment-ordered fp16 plane, row n' = h*NC + comp.
// ---------------------------------------------------------------------------
template<int NC>
__global__ __launch_bounds__(256)
void wsplit_t(const float* __restrict__ W, _Float16* __restrict__ Wt, int K) {
    __shared__ _Float16 tile[32][132];
    const int N  = NC * 1024;
    const int KT = K >> 4;
    const int rt = blockIdx.x, kc = blockIdx.y;

    const int nl = threadIdx.x & 31;
    const int kl = threadIdx.x >> 5;
    const int np = rt * 32 + nl;
    const int h  = np / NC, comp = np - h * NC;
    const int n  = comp * 1024 + h;
    #pragma unroll
    for (int kk = 0; kk < 16; ++kk) {
        const int k = kc * 128 + kl * 16 + kk;
        tile[nl][kl * 16 + kk] = (_Float16)W[(size_t)k * N + n];
    }
    __syncthreads();

    #pragma unroll
    for (int p = 0; p < 2; ++p) {
        const int slot = p * 256 + threadIdx.x;
        const int ktl  = slot >> 6, l = slot & 63;
        f16x8 v;
        #pragma unroll
        for (int j = 0; j < 8; ++j)
            v[j] = tile[l & 31][ktl * 16 + ((l >> 5) << 3) + j];
        const int kt = kc * 8 + ktl;
        *(f16x8*)&Wt[((size_t)rt * KT + kt) * 512 + l * 8] = v;
    }
}

// ---------------------------------------------------------------------------
// x (rows x 512 fp32 row-major) -> fragment-ordered fp16.
// ---------------------------------------------------------------------------
__global__ __launch_bounds__(256)
void esplit(const float* __restrict__ src, _Float16* __restrict__ dst) {
    __shared__ _Float16 tile[32][132];
    const int rt = blockIdx.x, kc = blockIdx.y;
    const int kli = threadIdx.x & 31;
    const int rl  = threadIdx.x >> 5;
    #pragma unroll
    for (int rr = 0; rr < 4; ++rr) {
        const int row = rl * 4 + rr;
        const float4 v = *(const float4*)&src[(size_t)(rt * 32 + row) * 512 + kc * 128 + kli * 4];
        tile[row][kli * 4 + 0] = (_Float16)v.x;
        tile[row][kli * 4 + 1] = (_Float16)v.y;
        tile[row][kli * 4 + 2] = (_Float16)v.z;
        tile[row][kli * 4 + 3] = (_Float16)v.w;
    }
    __syncthreads();

    #pragma unroll
    for (int p = 0; p < 2; ++p) {
        const int slot = p * 256 + threadIdx.x;
        const int ktl  = slot >> 6, l = slot & 63;
        f16x8 v;
        #pragma unroll
        for (int j = 0; j < 8; ++j)
            v[j] = tile[l & 31][ktl * 16 + ((l >> 5) << 3) + j];
        const int kt = kc * 8 + ktl;
        *(f16x8*)&dst[((size_t)rt * 32 + kt) * 512 + l * 8] = v;
    }
}

// ---------------------------------------------------------------------------
// Final FC on time-averaged h: out[b,c] = hbar[b,:] . fc_w[:,c] + fc_b[c]
// ---------------------------------------------------------------------------
__global__ __launch_bounds__(64)
void final_fc(const float* __restrict__ hbar, const float* __restrict__ fcw,
              const float* __restrict__ fcb, float* __restrict__ out) {
    __shared__ float hrow[HIDN];
    const int b = blockIdx.x;
    for (int i = threadIdx.x; i < HIDN; i += 64)
        hrow[i] = hbar[(size_t)b * HIDN + i];
    __syncthreads();

    const int c = threadIdx.x;
    if (c < NCLASS) {
        float acc = fcb[c];
        #pragma unroll 8
        for (int k = 0; k < HIDN; ++k)
            acc = fmaf(hrow[k], fcw[(size_t)k * NCLASS + c], acc);
        out[(size_t)b * NCLASS + c] = acc;
    }
}

// ---------------------------------------------------------------------------
extern "C" void kernel_launch(void* const* d_in, const int* in_sizes, int n_in,
                              void* d_out, int out_size, void* d_ws, size_t ws_size,
                              hipStream_t stream) {
    const float* x   = (const float*)d_in[0];
    const float* W0  = (const float*)d_in[1];
    const float* W1  = (const float*)d_in[2];
    const float* W2  = (const float*)d_in[3];
    const float* vc0 = (const float*)d_in[4];
    const float* vc1 = (const float*)d_in[5];
    const float* vc2 = (const float*)d_in[6];
    const float* b0  = (const float*)d_in[7];
    const float* b1  = (const float*)d_in[8];
    const float* b2  = (const float*)d_in[9];
    const float* fcw = (const float*)d_in[10];
    const float* fcb = (const float*)d_in[11];
    float* out = (float*)d_out;

    char* ws = (char*)d_ws;
    size_t off = 0;
    auto carve = [&](size_t bytes) { char* p = ws + off; off = (off + bytes + 255) & ~255ull; return p; };

    _Float16* W0t = (_Float16*)carve((size_t)4096 * 512 * 2);
    _Float16* W1t = (_Float16*)carve((size_t)3072 * 1024 * 2);
    _Float16* W2t = (_Float16*)carve((size_t)3072 * 1024 * 2);
    const size_t W_BYTES = off;

    const size_t PER_B = 12ull * 512 * 2 + 2ull * 12 * 1024 * 2 + 1024ull * 4 + 1024;
    int CB = 32;
    if      (W_BYTES + 2048ull * PER_B <= ws_size) CB = 2048;
    else if (W_BYTES + 1024ull * PER_B <= ws_size) CB = 1024;
    else if (W_BYTES +  512ull * PER_B <= ws_size) CB = 512;
    else if (W_BYTES +  256ull * PER_B <= ws_size) CB = 256;
    else if (W_BYTES +  128ull * PER_B <= ws_size) CB = 128;
    else if (W_BYTES +   64ull * PER_B <= ws_size) CB = 64;
    const int MC = CB * TSTEPS;

    _Float16* x16  = (_Float16*)carve((size_t)MC * 512 * 2);
    _Float16* hA16 = (_Float16*)carve((size_t)MC * 1024 * 2);
    _Float16* hB16 = (_Float16*)carve((size_t)MC * 1024 * 2);
    float*    hbar = (float*)carve((size_t)CB * 1024 * 4);

    const dim3 blk256(256);

    wsplit_t<4><<<dim3(4096 / 32, 512 / 128),  blk256, 0, stream>>>(W0, W0t, 512);
    wsplit_t<3><<<dim3(3072 / 32, 1024 / 128), blk256, 0, stream>>>(W1, W1t, 1024);
    wsplit_t<3><<<dim3(3072 / 32, 1024 / 128), blk256, 0, stream>>>(W2, W2t, 1024);

    for (int cb = 0; cb < BATCH / CB; ++cb) {
        const float* xc   = x   + (size_t)cb * CB * TSTEPS * IMG;
        float*       outc = out + (size_t)cb * CB * NCLASS;

        // layer 0: x -> fragment fp16; fused GEMM(K=512, BN=128, NCOMP=4)
        esplit<<<dim3(MC / 32, 4), blk256, 0, stream>>>(xc, x16);
        gemm_sru<2, 4><<<dim3(4096 / 128, MC / 192), blk256, 0, stream>>>(
            x16, W0t, nullptr, vc0, b0, hA16, nullptr, 512, 2);   // pc=4

        // layer 1: fused GEMM(K=1024, BN=192, NCOMP=3)
        gemm_sru<3, 3><<<dim3(3072 / 192, MC / 192), blk256, 0, stream>>>(
            hA16, W1t, hA16, vc1, b1, hB16, nullptr, 1024, 1);    // pc=2

        // layer 2: fused; emit hbar only
        gemm_sru<3, 3><<<dim3(3072 / 192, MC / 192), blk256, 0, stream>>>(
            hB16, W2t, hB16, vc2, b2, nullptr, hbar, 1024, 1);

        final_fc<<<dim3(CB), dim3(64), 0, stream>>>(hbar, fcw, fcb, outc);
    }
}

// Round 7
// 760.440 us; speedup vs baseline: 1.3809x; 1.3447x over previous
//
#include <hip/hip_runtime.h>
#include <math.h>

#define TSTEPS 12
#define BATCH  2048
#define IMG    512
#define HIDN   1024
#define NCLASS 51
#define SCALE_X 1.7320508075688772f      // sqrt(1 + 2*e^0) = sqrt(3)

typedef __attribute__((ext_vector_type(8)))  _Float16 f16x8;
typedef __attribute__((ext_vector_type(2)))  _Float16 f16x2;
typedef __attribute__((ext_vector_type(16))) float    f32x16;

__device__ __forceinline__ float sigf(float x) {
    return 1.f / (1.f + __expf(-x));
}

// s_waitcnt imm: vmcnt low bits [3:0], hi bits [15:14]; lgkmcnt=15 (no wait),
// expcnt=7 (no wait). Supports n up to 63.
#define VMCNT_IMM(n) (0x0F70 | ((n) & 15) | (((n) >> 4) << 14))

// ===========================================================================
// Fragment-ordered layout: matrix [R x K] fp16 stored as 1KB chunks over
// (rt=row/32, kt=k/16); chunk idx = rt*(K/16)+kt; lane l owns halfs
// [l*8,l*8+8) = (row = rt*32+(l&31), k = kt*16+(l>>5)*8+j). Matches the
// v_mfma_f32_32x32x16_f16 A/B fragment.
// ===========================================================================

// ---------------------------------------------------------------------------
// Fused fp16 MFMA GEMM + SRU recurrence. 32x32x16 MFMA.
//
// R16: ZERO VGPR-path global loads in the K-loop. Evidence (R3 vs R6):
// R6 moved A to direct VGPR loads -> +56% time on +33% bytes with HBM/L2
// util DOWN -- VGPR-return loads are latency-serialized (unified reg file
// at 256/wave leaves ~0 prefetch depth). R3's residual stall was its B
// loads (24KB/chunk) on that same path. Fix: stage BOTH A and B into LDS
// via global_load_lds DMA (deep queue, one counted vmcnt, no registers),
// read operands via conflict-free ds_read_b128 (chunk reads are
// lane-stride-1). Per-CU per 32-k step: MFMA 1162 cyc vs DMA 48KB ~750 cyc
// -> MFMA-bound on paper.
// Structure = R3-proven skeleton: BK=32, 3-buffer ring (A 12KB + B 4TJ KB
// per buffer), ONE vmcnt+barrier per step, stage lead 2 (~2 steps ~3000cy).
// vmcnt: only stage ops exist -> top-of-step vmcnt(NL) forces own stage(v)
// (stage(v+1) outstanding); LAST step uses vmcnt(0) (tail-corrected -- R3's
// constant-count wait was racy on the final steps).
// Requires K % 64 == 0 (NSTEP even not required; 512, 1024 here).
// ---------------------------------------------------------------------------
template<int TJ, int NCOMP>
__global__ __launch_bounds__(256, 2)
void gemm_sru(const _Float16* __restrict__ A, const _Float16* __restrict__ Bt,
              const _Float16* __restrict__ resid,
              const float* __restrict__ vc, const float* __restrict__ bias,
              _Float16* __restrict__ hout, float* __restrict__ hbar, int K,
              int pcshift) {
    constexpr int BN    = 64 * TJ;
    constexpr int NCH   = BN / NCOMP;
    constexpr int ACH   = 12;                  // A chunks per 32-k step (6 rc x 2 kt)
    constexpr int BCH   = 2 * TJ;              // B col-chunks x 2 kt ... = 2*TJ*... 
    constexpr int BCH2  = 2 * BCH;             // B chunks per step (2TJ cols? no:)
    // B chunks per step = (BN/32) col-chunks * 2 kt = 2*TJ*2? BN/32 = 2TJ.
    constexpr int NCHK  = ACH + (BN >> 5) * 2; // 20 (TJ=2) or 24 (TJ=3)
    constexpr int NL    = NCHK / 4;            // DMA loads per wave per step
    constexpr int STEP  = NCHK * 512;          // halfs per ring buffer
    constexpr int STG   = 3 * STEP;            // 3-buffer ring
    constexpr int EPAD  = BN + 8;
    constexpr int EPI   = 96 * EPAD;
    constexpr int HREG  = 96 * NCH;
    constexpr int KTH   = NCH / 16;
    constexpr int PAIRS = NCH / 2;
    constexpr int TOT   = STG > (EPI + HREG) ? STG : (EPI + HREG);
    __shared__ __align__(16) _Float16 smem[TOT];

    const int tid  = threadIdx.x;
    const int lane = tid & 63;
    const int w    = tid >> 6;

    // ---- XCD swizzle: columns ≡ xk (mod 8) stay on one XCD (W-stationary) --
    const int nbx = gridDim.x;
    const int b   = blockIdx.y * nbx + blockIdx.x;
    const int pc1 = (nbx >> 3) - 1;
    const int xk  = b & 7, s = b >> 3;
    const int bx  = xk + ((s & pc1) << 3);
    const int by  = s >> pcshift;

    const int bm  = by * 192;
    const int KT  = K >> 4;
    const int rt0 = bm >> 5;
    const int ct0 = bx * (BN >> 5);

    // ---- staging: A chunks c<ACH, B chunks c>=ACH; NL DMA ops per wave -----
    auto stage = [&](int buf, int k0) {
        const int kt0 = k0 >> 4;
        #pragma unroll
        for (int i = 0; i < NL; ++i) {
            const int c = w * NL + i;
            const _Float16* g;
            if (c < ACH) {
                const int rc = c >> 1, kk = c & 1;
                g = A + ((size_t)(rt0 + rc) * KT + kt0 + kk) * 512 + (lane << 3);
            } else {
                const int cc = (c - ACH) >> 1, kk = (c - ACH) & 1;
                g = Bt + ((size_t)(ct0 + cc) * KT + kt0 + kk) * 512 + (lane << 3);
            }
            __builtin_amdgcn_global_load_lds(
                (const __attribute__((address_space(1))) unsigned int*)g,
                (__attribute__((address_space(3))) unsigned int*)(smem + buf * STEP + c * 512),
                16, 0, 0);
        }
    };

    const int wy32 = (w >> 1) * 3;             // wave row-chunk origin
    const int wx32 = (w & 1) * TJ;             // wave col-chunk origin
    const int l5   = lane >> 5;
    const int m32  = lane & 31;

    f32x16 acc[3][TJ];
    #pragma unroll
    for (int i = 0; i < 3; ++i)
        #pragma unroll
        for (int j = 0; j < TJ; ++j)
            #pragma unroll
            for (int r = 0; r < 16; ++r) acc[i][j][r] = 0.f;

    const int NSTEP = K >> 5;                  // 32-k steps (16 or 32)

    stage(0, 0);
    stage(1, 32);

    int rb = 0, sb = 2;                        // read buf (v%3), stage buf ((v+2)%3)
    for (int v = 0; v < NSTEP; ++v) {
        // Force own stage(v) (in-order vmcnt). Steady state: stage(v+1)=NL
        // outstanding. Last step: nothing newer -> must wait to 0.
        if (v + 1 < NSTEP) __builtin_amdgcn_s_waitcnt(VMCNT_IMM(NL));
        else               __builtin_amdgcn_s_waitcnt(VMCNT_IMM(0));
        __builtin_amdgcn_s_barrier();

        const _Float16* la = smem + rb * STEP;
        const _Float16* lb = la + ACH * 512;
        if (v + 2 < NSTEP) stage(sb, (v + 2) << 5);

        #pragma unroll
        for (int ks = 0; ks < 2; ++ks) {
            f16x8 av[3], bv[TJ];
            #pragma unroll
            for (int i = 0; i < 3; ++i)
                av[i] = *(const f16x8*)&la[((wy32 + i) * 2 + ks) * 512 + (lane << 3)];
            #pragma unroll
            for (int j = 0; j < TJ; ++j)
                bv[j] = *(const f16x8*)&lb[((wx32 + j) * 2 + ks) * 512 + (lane << 3)];
            #pragma unroll
            for (int i = 0; i < 3; ++i)
                #pragma unroll
                for (int j = 0; j < TJ; ++j)
                    acc[i][j] = __builtin_amdgcn_mfma_f32_32x32x16_f16(
                        av[i], bv[j], acc[i][j], 0, 0, 0);
        }

        rb = (rb == 2) ? 0 : rb + 1;
        sb = (sb == 2) ? 0 : sb + 1;
    }

    // ---- epilogue: two passes of 96 rows (8 whole batches each) ------------
    _Float16 (*uld)[EPAD] = (_Float16 (*)[EPAD])smem;
    _Float16* hreg = smem + EPI;
    const int bl   = tid / PAIRS;
    const int pr   = tid % PAIRS;
    const int gcol = bx * NCH + pr * 2;

    #pragma unroll
    for (int pass = 0; pass < 2; ++pass) {
        __syncthreads();
        if ((w >> 1) == pass) {
            #pragma unroll
            for (int i = 0; i < 3; ++i)
                #pragma unroll
                for (int j = 0; j < TJ; ++j)
                    #pragma unroll
                    for (int r = 0; r < 16; ++r) {
                        const int row = i * 32 + (r & 3) + 8 * (r >> 2) + 4 * l5;
                        uld[row][(wx32 + j) * 32 + m32] = (_Float16)acc[i][j][r];
                    }
        }
        __syncthreads();

        if (tid < 8 * PAIRS) {
            const float2 vf  = *(const float2*)&vc[gcol];
            const float2 vr  = *(const float2*)&vc[HIDN + gcol];
            const float2 bfv = *(const float2*)&bias[gcol];
            const float2 brv = *(const float2*)&bias[HIDN + gcol];
            const int ca = (pr * 2) * NCOMP, cb = (pr * 2 + 1) * NCOMP;

            float c0 = 0.f, c1 = 0.f, s0 = 0.f, s1 = 0.f;
            #pragma unroll
            for (int t = 0; t < TSTEPS; ++t) {
                const int row = bl * 12 + t;
                const float u0a = (float)uld[row][ca + 0];
                const float u1a = (float)uld[row][ca + 1];
                const float u2a = (float)uld[row][ca + 2];
                const float u0b = (float)uld[row][cb + 0];
                const float u1b = (float)uld[row][cb + 1];
                const float u2b = (float)uld[row][cb + 2];
                float xta, xtb;
                if (NCOMP == 4) {
                    xta = (float)uld[row][ca + 3];
                    xtb = (float)uld[row][cb + 3];
                } else {
                    const int grow = bm + pass * 96 + row;
                    const size_t gran = ((size_t)(grow >> 5) * KT + (gcol >> 4)) * 512
                                      + (size_t)((grow & 31) + ((gcol >> 3) & 1) * 32) * 8
                                      + (gcol & 7);
                    const f16x2 xv = *(const f16x2*)&resid[gran];
                    xta = (float)xv[0]; xtb = (float)xv[1];
                }

                const float f0 = sigf(u1a + vf.x * c0 + bfv.x);
                c0 = f0 * c0 + (1.f - f0) * u0a;
                const float r0_ = sigf(u2a + vr.x * c0 + brv.x);
                const float th0 = 2.f * sigf(2.f * c0) - 1.f;
                const float hv0 = r0_ * th0 + (1.f - r0_) * xta * SCALE_X;

                const float f1 = sigf(u1b + vf.y * c1 + bfv.y);
                c1 = f1 * c1 + (1.f - f1) * u0b;
                const float r1_ = sigf(u2b + vr.y * c1 + brv.y);
                const float th1 = 2.f * sigf(2.f * c1) - 1.f;
                const float hv1 = r1_ * th1 + (1.f - r1_) * xtb * SCALE_X;

                if (hout) {
                    const int rtl  = row >> 5;
                    const int ktl  = pr >> 3;
                    const int lloc = (row & 31) + ((pr >> 2) & 1) * 32;
                    f16x2 hv = { (_Float16)hv0, (_Float16)hv1 };
                    *(f16x2*)&hreg[(rtl * KTH + ktl) * 512 + lloc * 8 + (pr & 3) * 2] = hv;
                }
                s0 += hv0; s1 += hv1;
            }
            if (hbar) {
                const int gb = bm / 12 + pass * 8 + bl;
                *(float2*)&hbar[(size_t)gb * HIDN + gcol] =
                    make_float2(s0 * (1.f / TSTEPS), s1 * (1.f / TSTEPS));
            }
        }

        if (hout) {
            __syncthreads();
            const int rtg0 = (bm + pass * 96) >> 5;
            for (int g = tid; g < HREG / 8; g += 256) {
                const int c = g >> 6, l = g & 63;
                const f16x8 v = *(const f16x8*)&hreg[c * 512 + l * 8];
                const int rtl = c / KTH, ktl = c % KTH;
                const size_t gc = (size_t)(rtg0 + rtl) * 64 + bx * KTH + ktl;
                *(f16x8*)&hout[gc * 512 + l * 8] = v;
            }
        }
    }
}

// ---------------------------------------------------------------------------
// Weight prep (coalesced, LDS transpose): W (K x N fp32, col n = comp*1024+h)
// -> fragment-ordered fp16 plane, row n' = h*NC + comp.
// ---------------------------------------------------------------------------
template<int NC>
__global__ __launch_bounds__(256)
void wsplit_t(const float* __restrict__ W, _Float16* __restrict__ Wt, int K) {
    __shared__ _Float16 tile[32][132];
    const int N  = NC * 1024;
    const int KT = K >> 4;
    const int rt = blockIdx.x, kc = blockIdx.y;

    const int nl = threadIdx.x & 31;
    const int kl = threadIdx.x >> 5;
    const int np = rt * 32 + nl;
    const int h  = np / NC, comp = np - h * NC;
    const int n  = comp * 1024 + h;
    #pragma unroll
    for (int kk = 0; kk < 16; ++kk) {
        const int k = kc * 128 + kl * 16 + kk;
        tile[nl][kl * 16 + kk] = (_Float16)W[(size_t)k * N + n];
    }
    __syncthreads();

    #pragma unroll
    for (int p = 0; p < 2; ++p) {
        const int slot = p * 256 + threadIdx.x;
        const int ktl  = slot >> 6, l = slot & 63;
        f16x8 v;
        #pragma unroll
        for (int j = 0; j < 8; ++j)
            v[j] = tile[l & 31][ktl * 16 + ((l >> 5) << 3) + j];
        const int kt = kc * 8 + ktl;
        *(f16x8*)&Wt[((size_t)rt * KT + kt) * 512 + l * 8] = v;
    }
}

// ---------------------------------------------------------------------------
// x (rows x 512 fp32 row-major) -> fragment-ordered fp16.
// ---------------------------------------------------------------------------
__global__ __launch_bounds__(256)
void esplit(const float* __restrict__ src, _Float16* __restrict__ dst) {
    __shared__ _Float16 tile[32][132];
    const int rt = blockIdx.x, kc = blockIdx.y;
    const int kli = threadIdx.x & 31;
    const int rl  = threadIdx.x >> 5;
    #pragma unroll
    for (int rr = 0; rr < 4; ++rr) {
        const int row = rl * 4 + rr;
        const float4 v = *(const float4*)&src[(size_t)(rt * 32 + row) * 512 + kc * 128 + kli * 4];
        tile[row][kli * 4 + 0] = (_Float16)v.x;
        tile[row][kli * 4 + 1] = (_Float16)v.y;
        tile[row][kli * 4 + 2] = (_Float16)v.z;
        tile[row][kli * 4 + 3] = (_Float16)v.w;
    }
    __syncthreads();

    #pragma unroll
    for (int p = 0; p < 2; ++p) {
        const int slot = p * 256 + threadIdx.x;
        const int ktl  = slot >> 6, l = slot & 63;
        f16x8 v;
        #pragma unroll
        for (int j = 0; j < 8; ++j)
            v[j] = tile[l & 31][ktl * 16 + ((l >> 5) << 3) + j];
        const int kt = kc * 8 + ktl;
        *(f16x8*)&dst[((size_t)rt * 32 + kt) * 512 + l * 8] = v;
    }
}

// ---------------------------------------------------------------------------
// Final FC on time-averaged h: out[b,c] = hbar[b,:] . fc_w[:,c] + fc_b[c]
// ---------------------------------------------------------------------------
__global__ __launch_bounds__(64)
void final_fc(const float* __restrict__ hbar, const float* __restrict__ fcw,
              const float* __restrict__ fcb, float* __restrict__ out) {
    __shared__ float hrow[HIDN];
    const int b = blockIdx.x;
    for (int i = threadIdx.x; i < HIDN; i += 64)
        hrow[i] = hbar[(size_t)b * HIDN + i];
    __syncthreads();

    const int c = threadIdx.x;
    if (c < NCLASS) {
        float acc = fcb[c];
        #pragma unroll 8
        for (int k = 0; k < HIDN; ++k)
            acc = fmaf(hrow[k], fcw[(size_t)k * NCLASS + c], acc);
        out[(size_t)b * NCLASS + c] = acc;
    }
}

// ---------------------------------------------------------------------------
extern "C" void kernel_launch(void* const* d_in, const int* in_sizes, int n_in,
                              void* d_out, int out_size, void* d_ws, size_t ws_size,
                              hipStream_t stream) {
    const float* x   = (const float*)d_in[0];
    const float* W0  = (const float*)d_in[1];
    const float* W1  = (const float*)d_in[2];
    const float* W2  = (const float*)d_in[3];
    const float* vc0 = (const float*)d_in[4];
    const float* vc1 = (const float*)d_in[5];
    const float* vc2 = (const float*)d_in[6];
    const float* b0  = (const float*)d_in[7];
    const float* b1  = (const float*)d_in[8];
    const float* b2  = (const float*)d_in[9];
    const float* fcw = (const float*)d_in[10];
    const float* fcb = (const float*)d_in[11];
    float* out = (float*)d_out;

    char* ws = (char*)d_ws;
    size_t off = 0;
    auto carve = [&](size_t bytes) { char* p = ws + off; off = (off + bytes + 255) & ~255ull; return p; };

    _Float16* W0t = (_Float16*)carve((size_t)4096 * 512 * 2);
    _Float16* W1t = (_Float16*)carve((size_t)3072 * 1024 * 2);
    _Float16* W2t = (_Float16*)carve((size_t)3072 * 1024 * 2);
    const size_t W_BYTES = off;

    const size_t PER_B = 12ull * 512 * 2 + 2ull * 12 * 1024 * 2 + 1024ull * 4 + 1024;
    int CB = 32;
    if      (W_BYTES + 2048ull * PER_B <= ws_size) CB = 2048;
    else if (W_BYTES + 1024ull * PER_B <= ws_size) CB = 1024;
    else if (W_BYTES +  512ull * PER_B <= ws_size) CB = 512;
    else if (W_BYTES +  256ull * PER_B <= ws_size) CB = 256;
    else if (W_BYTES +  128ull * PER_B <= ws_size) CB = 128;
    else if (W_BYTES +   64ull * PER_B <= ws_size) CB = 64;
    const int MC = CB * TSTEPS;

    _Float16* x16  = (_Float16*)carve((size_t)MC * 512 * 2);
    _Float16* hA16 = (_Float16*)carve((size_t)MC * 1024 * 2);
    _Float16* hB16 = (_Float16*)carve((size_t)MC * 1024 * 2);
    float*    hbar = (float*)carve((size_t)CB * 1024 * 4);

    const dim3 blk256(256);

    wsplit_t<4><<<dim3(4096 / 32, 512 / 128),  blk256, 0, stream>>>(W0, W0t, 512);
    wsplit_t<3><<<dim3(3072 / 32, 1024 / 128), blk256, 0, stream>>>(W1, W1t, 1024);
    wsplit_t<3><<<dim3(3072 / 32, 1024 / 128), blk256, 0, stream>>>(W2, W2t, 1024);

    for (int cb = 0; cb < BATCH / CB; ++cb) {
        const float* xc   = x   + (size_t)cb * CB * TSTEPS * IMG;
        float*       outc = out + (size_t)cb * CB * NCLASS;

        // layer 0: x -> fragment fp16; fused GEMM(K=512, BN=128, NCOMP=4)
        esplit<<<dim3(MC / 32, 4), blk256, 0, stream>>>(xc, x16);
        gemm_sru<2, 4><<<dim3(4096 / 128, MC / 192), blk256, 0, stream>>>(
            x16, W0t, nullptr, vc0, b0, hA16, nullptr, 512, 2);   // pc=4

        // layer 1: fused GEMM(K=1024, BN=192, NCOMP=3)
        gemm_sru<3, 3><<<dim3(3072 / 192, MC / 192), blk256, 0, stream>>>(
            hA16, W1t, hA16, vc1, b1, hB16, nullptr, 1024, 1);    // pc=2

        // layer 2: fused; emit hbar only
        gemm_sru<3, 3><<<dim3(3072 / 192, MC / 192), blk256, 0, stream>>>(
            hB16, W2t, hB16, vc2, b2, nullptr, hbar, 1024, 1);

        final_fc<<<dim3(CB), dim3(64), 0, stream>>>(hbar, fcw, fcb, outc);
    }
}